// Round 1
// baseline (667.860 us; speedup 1.0000x reference)
//
#include <hip/hip_runtime.h>

// y[i] = dot(x[i, 0:32], w[0:32]) + w[32]
// x: [N, 32] fp32 row-major, w: [33, 1] fp32, y: [N] fp32
// Memory-bound: 512 MB read + 16 MB write -> roofline ~84 us @ 6.3 TB/s.
//
// Layout: 8 lanes per row. Lane (t&7) loads float4 #(t&7) of the row ->
// consecutive lanes hit consecutive 16B chunks (fully coalesced, 1KB/wave
// per load instruction). 3-step shfl_xor reduce within the 8-lane group,
// group-lane 0 stores the scalar result.

__global__ __launch_bounds__(256) void linreg_fwd_kernel(
    const float* __restrict__ x,
    const float* __restrict__ w,
    float* __restrict__ y,
    int n_rows)
{
    const int lane8 = threadIdx.x & 7;

    // Per-thread weight fragment: w[lane8*4 .. lane8*4+3], plus bias w[32].
    const float4 wv = reinterpret_cast<const float4*>(w)[lane8];
    const float bias = w[32];

    const int gid = blockIdx.x * blockDim.x + threadIdx.x;
    const int group = gid >> 3;                          // one group = one row
    const int groups_per_grid = (gridDim.x * blockDim.x) >> 3;

    const float4* __restrict__ x4 = reinterpret_cast<const float4*>(x);

    for (int row = group; row < n_rows; row += groups_per_grid) {
        // row*32 floats = row*8 float4s; lane8 picks this thread's chunk.
        const float4 xv = x4[(size_t)row * 8 + lane8];
        float p = xv.x * wv.x + xv.y * wv.y + xv.z * wv.z + xv.w * wv.w;
        // Reduce across the 8-lane group (within the 64-lane wave).
        p += __shfl_xor(p, 1);
        p += __shfl_xor(p, 2);
        p += __shfl_xor(p, 4);
        if (lane8 == 0) {
            y[row] = p + bias;
        }
    }
}

extern "C" void kernel_launch(void* const* d_in, const int* in_sizes, int n_in,
                              void* d_out, int out_size, void* d_ws, size_t ws_size,
                              hipStream_t stream) {
    const float* x = (const float*)d_in[0];  // [N, 32]
    const float* w = (const float*)d_in[1];  // [33, 1]
    float* y = (float*)d_out;                // [N, 1]

    const int n_rows = in_sizes[0] / 32;     // 4,194,304

    // 2048 blocks x 256 threads = 8192 waves = full occupancy on 256 CUs.
    const int block = 256;
    const int grid = 2048;
    linreg_fwd_kernel<<<grid, block, 0, stream>>>(x, w, y, n_rows);
}